// Round 1
// baseline (691.865 us; speedup 1.0000x reference)
//
#include <hip/hip_runtime.h>

#define NN 200000
#define NE 600000
#define DD 128
#define NT (NN/64)   // 3125 row tiles (exact)

constexpr float BN_EPS = 1e-5f;

// ---------------- init / degree / stats ----------------

__global__ void k_zero(int* __restrict__ cnt, float* __restrict__ ssum, float* __restrict__ ssq) {
  int i = blockIdx.x*256 + threadIdx.x;
  if (i < NN) cnt[i] = 0;
  if (i < DD) { ssum[i] = 0.f; ssq[i] = 0.f; }
}

__global__ void k_count(const int* __restrict__ ei, int* __restrict__ cnt) {
  int e = blockIdx.x*256 + threadIdx.x;
  if (e < NE) atomicAdd(&cnt[ei[NE + e]], 1);
}

// column sums of prelu(x, a1): ssum[c], ssq[c]
__global__ void k_stats(const float* __restrict__ x, const float* __restrict__ a1p,
                        float* __restrict__ ssum, float* __restrict__ ssq) {
  __shared__ float s1[256], s2[256];
  int col  = threadIdx.x & 127;
  int half = threadIdx.x >> 7;
  float a1 = *a1p;
  float acc1 = 0.f, acc2 = 0.f;
  int stride = gridDim.x * 2;
  for (int r = blockIdx.x*2 + half; r < NN; r += stride) {
    float v = x[(size_t)r*DD + col];
    v = (v >= 0.f) ? v : a1*v;
    acc1 += v; acc2 += v*v;
  }
  s1[threadIdx.x] = acc1; s2[threadIdx.x] = acc2;
  __syncthreads();
  if (threadIdx.x < 128) {
    atomicAdd(&ssum[col], s1[threadIdx.x] + s1[threadIdx.x + 128]);
    atomicAdd(&ssq [col], s2[threadIdx.x] + s2[threadIdx.x + 128]);
  }
}

// BN params s,t and tw1[j] = sum_k t[k] * W1[k,j]   (single block, 128 threads)
__global__ void k_bn_tw1(const float* __restrict__ ssum, const float* __restrict__ ssq,
                         const float* __restrict__ gamma, const float* __restrict__ beta,
                         const float* __restrict__ W1,
                         float* __restrict__ sarr, float* __restrict__ tarr,
                         float* __restrict__ tw1) {
  __shared__ float ts[128];
  int j = threadIdx.x;
  float mean = ssum[j] * (1.f/NN);
  float var  = ssq[j] * (1.f/NN) - mean*mean;
  float s = gamma[j] * rsqrtf(var + BN_EPS);
  float t = beta[j] - mean*s;
  sarr[j] = s; tarr[j] = t; ts[j] = t;
  __syncthreads();
  float acc = 0.f;
  for (int k = 0; k < 128; ++k) acc += ts[k] * W1[k*DD + j];
  tw1[j] = acc;
}

__global__ void k_dinv(const int* __restrict__ cnt, float* __restrict__ dinv) {
  int i = blockIdx.x*256 + threadIdx.x;
  if (i < NN) dinv[i] = rsqrtf((float)(cnt[i] + 1));
}

// ---------------- exclusive scan (3 pass) ----------------

__global__ void k_scan1(const int* __restrict__ cnt, int* __restrict__ rp, int* __restrict__ bsums) {
  __shared__ int sm[256];
  int tid = threadIdx.x;
  int base = blockIdx.x*1024 + tid*4;
  int4 v = make_int4(0,0,0,0);
  if (base + 3 < NN) v = *(const int4*)(cnt + base);
  else {
    if (base   < NN) v.x = cnt[base];
    if (base+1 < NN) v.y = cnt[base+1];
    if (base+2 < NN) v.z = cnt[base+2];
    if (base+3 < NN) v.w = cnt[base+3];
  }
  int p1 = v.x, p2 = p1 + v.y, p3 = p2 + v.z, tsum = p3 + v.w;
  sm[tid] = tsum; __syncthreads();
  for (int off = 1; off < 256; off <<= 1) {
    int t = (tid >= off) ? sm[tid - off] : 0; __syncthreads();
    sm[tid] += t; __syncthreads();
  }
  int inc = sm[tid];
  int excl = inc - tsum;
  if (base   < NN) rp[base]   = excl;
  if (base+1 < NN) rp[base+1] = excl + p1;
  if (base+2 < NN) rp[base+2] = excl + p2;
  if (base+3 < NN) rp[base+3] = excl + p3;
  if (tid == 255) bsums[blockIdx.x] = inc;
}

__global__ void k_scan2(int* __restrict__ bsums, int nb) {
  __shared__ int sm[256];
  int tid = threadIdx.x;
  int v = (tid < nb) ? bsums[tid] : 0;
  sm[tid] = v; __syncthreads();
  for (int off = 1; off < 256; off <<= 1) {
    int t = (tid >= off) ? sm[tid - off] : 0; __syncthreads();
    sm[tid] += t; __syncthreads();
  }
  if (tid < nb) bsums[tid] = sm[tid] - v;   // exclusive
}

__global__ void k_scan3(int* __restrict__ rp, const int* __restrict__ bsums, int* __restrict__ cur) {
  int i = blockIdx.x*256 + threadIdx.x;
  if (i < NN) {
    int val = rp[i] + bsums[i >> 10];
    rp[i] = val; cur[i] = val;
  }
  if (i == 0) rp[NN] = NE;
}

__global__ void k_fill(const int* __restrict__ ei, const float* __restrict__ dinv,
                       int* __restrict__ cur, int2* __restrict__ pairs) {
  int e = blockIdx.x*256 + threadIdx.x;
  if (e < NE) {
    int s = ei[e], d = ei[NE + e];
    int pos = atomicAdd(&cur[d], 1);
    float cf = dinv[s] * dinv[d];
    pairs[pos] = make_int2(s, __float_as_int(cf));
  }
}

// ---------------- GEMM: C[N,128] = A'[N,128] @ W[128,128] (+ row add) ----------------
// A' = FUSE ? s[c]*prelu(A,a1) : A.  Persistent blocks, 64-row tiles, K split in halves.
// LDS: Wl[64][132] (33.8KB) + As[64][68] (17.4KB) = 51.2KB < 64KB/WG.

template<bool FUSE, bool ADDROW>
__global__ __launch_bounds__(256)
void k_gemm(const float* __restrict__ A, const float* __restrict__ W,
            float* __restrict__ C, const float* __restrict__ sarr,
            const float* __restrict__ tw1, const float* __restrict__ a1p)
{
  __shared__ float Wl[64][132];
  __shared__ float As[64][68];
  const int tid = threadIdx.x;
  const int c  = (tid & 31) << 2;   // fixed col group 0..124 (loads)
  const int rb = tid >> 5;          // 0..7 (loads)
  const int tc = tid & 15;          // compute: 16 col groups
  const int tr = tid >> 4;          // compute: 16 row groups
  const int j0 = tc << 2;
  const int r0 = tr << 2;

  float a1v = 0.f;
  float4 sv = make_float4(1.f, 1.f, 1.f, 1.f);
  if constexpr (FUSE) { a1v = *a1p; sv = *(const float4*)(sarr + c); }
  float tw[8] = {0,0,0,0,0,0,0,0};
  if constexpr (ADDROW) {
    float4 t0 = *(const float4*)(tw1 + j0);
    float4 t1 = *(const float4*)(tw1 + j0 + 64);
    tw[0]=t0.x; tw[1]=t0.y; tw[2]=t0.z; tw[3]=t0.w;
    tw[4]=t1.x; tw[5]=t1.y; tw[6]=t1.z; tw[7]=t1.w;
  }

  float4 pf[8];
  {
    const float* ap = A + (size_t)blockIdx.x*64*DD + rb*DD + c;
    #pragma unroll
    for (int i = 0; i < 8; ++i) pf[i] = *(const float4*)(ap + i*8*DD);
  }

  for (int t = blockIdx.x; t < NT; t += gridDim.x) {
    float acc[4][8];
    #pragma unroll
    for (int i = 0; i < 4; ++i)
      #pragma unroll
      for (int j = 0; j < 8; ++j) acc[i][j] = 0.f;

    #pragma unroll
    for (int kh = 0; kh < 2; ++kh) {
      __syncthreads();
      // stage W half (rows kh*64..kh*64+63) — L2-broadcast re-read, cheap
      {
        const float* wp = W + (size_t)(kh*64 + rb)*DD + c;
        #pragma unroll
        for (int i = 0; i < 8; ++i) {
          float4 w = *(const float4*)(wp + i*8*DD);
          *(float4*)&Wl[rb + i*8][c] = w;
        }
      }
      // stage A half from prefetch regs (threads whose col group is in this half)
      if ((c >> 6) == kh) {
        int cc = c & 63;
        #pragma unroll
        for (int i = 0; i < 8; ++i) {
          float4 v = pf[i];
          if constexpr (FUSE) {
            v.x = (v.x >= 0.f ? v.x : a1v*v.x) * sv.x;
            v.y = (v.y >= 0.f ? v.y : a1v*v.y) * sv.y;
            v.z = (v.z >= 0.f ? v.z : a1v*v.z) * sv.z;
            v.w = (v.w >= 0.f ? v.w : a1v*v.w) * sv.w;
          }
          *(float4*)&As[rb + i*8][cc] = v;
        }
      }
      __syncthreads();
      if (kh == 1) {       // pf free now: prefetch next tile, overlaps compute
        int tn = t + gridDim.x;
        if (tn < NT) {
          const float* ap = A + (size_t)tn*64*DD + rb*DD + c;
          #pragma unroll
          for (int i = 0; i < 8; ++i) pf[i] = *(const float4*)(ap + i*8*DD);
        }
      }
      #pragma unroll 2
      for (int k = 0; k < 64; ++k) {
        float4 b0 = *(const float4*)&Wl[k][j0];
        float4 b1 = *(const float4*)&Wl[k][j0 + 64];
        float b[8] = {b0.x,b0.y,b0.z,b0.w,b1.x,b1.y,b1.z,b1.w};
        float a[4];
        a[0] = As[r0+0][k]; a[1] = As[r0+1][k];
        a[2] = As[r0+2][k]; a[3] = As[r0+3][k];
        #pragma unroll
        for (int i = 0; i < 4; ++i)
          #pragma unroll
          for (int j = 0; j < 8; ++j)
            acc[i][j] += a[i]*b[j];
      }
    }
    float* cp = C + (size_t)t*64*DD;
    #pragma unroll
    for (int i = 0; i < 4; ++i) {
      int row = r0 + i;
      float4 o0 = make_float4(acc[i][0]+tw[0], acc[i][1]+tw[1], acc[i][2]+tw[2], acc[i][3]+tw[3]);
      float4 o1 = make_float4(acc[i][4]+tw[4], acc[i][5]+tw[5], acc[i][6]+tw[6], acc[i][7]+tw[7]);
      *(float4*)(cp + (size_t)row*DD + j0)      = o0;
      *(float4*)(cp + (size_t)row*DD + j0 + 64) = o1;
    }
  }
}

// ---------------- aggregation: one wave per node ----------------
// out[i] = sum_{e in CSR(i)} coef_e * h[src_e] + dinv[i]^2 * h[i] + bias  (opt prelu a2)

template<bool PRELU>
__global__ __launch_bounds__(256)
void k_agg(const float* __restrict__ h, const int* __restrict__ rp,
           const int2* __restrict__ pairs, const float* __restrict__ dinv,
           const float* __restrict__ bias, const float* __restrict__ a2p,
           float* __restrict__ out)
{
  int wave = threadIdx.x >> 6;
  int lane = threadIdx.x & 63;
  int node = blockIdx.x*4 + wave;
  if (node >= NN) return;
  const float2* h2 = (const float2*)h;
  float2* o2 = (float2*)out;
  float di = dinv[node];
  int beg = rp[node], end = rp[node+1];
  float2 self = h2[(size_t)node*64 + lane];
  float sc = di*di;
  float ax = sc*self.x, ay = sc*self.y;
  for (int e = beg; e < end; ++e) {
    int2 pr = pairs[e];
    float cf = __int_as_float(pr.y);
    float2 hv = h2[(size_t)pr.x*64 + lane];
    ax += cf*hv.x; ay += cf*hv.y;
  }
  float2 b = ((const float2*)bias)[lane];
  ax += b.x; ay += b.y;
  if constexpr (PRELU) {
    float a2 = *a2p;
    ax = (ax >= 0.f) ? ax : a2*ax;
    ay = (ay >= 0.f) ? ay : a2*ay;
  }
  o2[(size_t)node*64 + lane] = make_float2(ax, ay);
}

// ---------------- launch ----------------

extern "C" void kernel_launch(void* const* d_in, const int* in_sizes, int n_in,
                              void* d_out, int out_size, void* d_ws, size_t ws_size,
                              hipStream_t stream) {
  const float* x     = (const float*)d_in[0];
  const int*   ei    = (const int*)  d_in[1];
  const float* a1    = (const float*)d_in[2];
  const float* gamma = (const float*)d_in[3];
  const float* beta  = (const float*)d_in[4];
  const float* W1    = (const float*)d_in[5];
  const float* b1    = (const float*)d_in[6];
  const float* a2    = (const float*)d_in[7];
  const float* W2    = (const float*)d_in[8];
  const float* b2    = (const float*)d_in[9];
  float* out = (float*)d_out;

  char* w = (char*)d_ws;
  auto alloc = [&](size_t bytes) { char* p = w; w += (bytes + 255) & ~(size_t)255; return p; };
  float* hbuf  = (float*)alloc((size_t)NN*DD*4);   // 102.4 MB
  float* dinv  = (float*)alloc((size_t)NN*4);
  int*   cnt   = (int*)  alloc((size_t)NN*4);
  int*   rp    = (int*)  alloc((size_t)(NN+1)*4);
  int*   cur   = (int*)  alloc((size_t)NN*4);
  int2*  pairs = (int2*) alloc((size_t)NE*8);
  int*   bsums = (int*)  alloc(256*4);
  float* ssum  = (float*)alloc(128*4);
  float* ssq   = (float*)alloc(128*4);
  float* sarr  = (float*)alloc(128*4);
  float* tarr  = (float*)alloc(128*4);
  float* tw1   = (float*)alloc(128*4);

  const int nblkN = (NN + 255)/256;
  const int nblkE = (NE + 255)/256;

  k_zero  <<<nblkN, 256, 0, stream>>>(cnt, ssum, ssq);
  k_count <<<nblkE, 256, 0, stream>>>(ei, cnt);
  k_stats <<<768,   256, 0, stream>>>(x, a1, ssum, ssq);
  k_bn_tw1<<<1,     128, 0, stream>>>(ssum, ssq, gamma, beta, W1, sarr, tarr, tw1);
  k_dinv  <<<nblkN, 256, 0, stream>>>(cnt, dinv);
  k_scan1 <<<196,   256, 0, stream>>>(cnt, rp, bsums);
  k_scan2 <<<1,     256, 0, stream>>>(bsums, 196);
  k_scan3 <<<nblkN, 256, 0, stream>>>(rp, bsums, cur);
  k_fill  <<<nblkE, 256, 0, stream>>>(ei, dinv, cur, pairs);

  k_gemm<true,  true ><<<768, 256, 0, stream>>>(x,   W1, hbuf, sarr, tw1, a1);
  k_agg <true >        <<<NN/4, 256, 0, stream>>>(hbuf, rp, pairs, dinv, b1, a2, out);
  k_gemm<false, false><<<768, 256, 0, stream>>>(out, W2, hbuf, nullptr, nullptr, nullptr);
  k_agg <false>        <<<NN/4, 256, 0, stream>>>(hbuf, rp, pairs, dinv, b2, nullptr, out);
}

// Round 3
// 677.104 us; speedup vs baseline: 1.0218x; 1.0218x over previous
//
#include <hip/hip_runtime.h>

#define NN 200000
#define NE 600000
#define DD 128
#define GT 1563   // ceil(NN/128) gemm row tiles

constexpr float BN_EPS = 1e-5f;

// ---------------- init / degree / stats ----------------

__global__ void k_zero(int* __restrict__ cnt, float* __restrict__ ssum, float* __restrict__ ssq) {
  int i = blockIdx.x*256 + threadIdx.x;
  if (i < NN) cnt[i] = 0;
  if (i < DD) { ssum[i] = 0.f; ssq[i] = 0.f; }
}

__global__ void k_count(const int* __restrict__ ei, int* __restrict__ cnt) {
  int e = blockIdx.x*256 + threadIdx.x;
  if (e < NE) atomicAdd(&cnt[ei[NE + e]], 1);
}

// column sums of prelu(x, a1): ssum[c], ssq[c]
__global__ void k_stats(const float* __restrict__ x, const float* __restrict__ a1p,
                        float* __restrict__ ssum, float* __restrict__ ssq) {
  __shared__ float s1[256], s2[256];
  int col  = threadIdx.x & 127;
  int half = threadIdx.x >> 7;
  float a1 = *a1p;
  float acc1 = 0.f, acc2 = 0.f;
  int stride = gridDim.x * 2;
  for (int r = blockIdx.x*2 + half; r < NN; r += stride) {
    float v = x[(size_t)r*DD + col];
    v = (v >= 0.f) ? v : a1*v;
    acc1 += v; acc2 += v*v;
  }
  s1[threadIdx.x] = acc1; s2[threadIdx.x] = acc2;
  __syncthreads();
  if (threadIdx.x < 128) {
    atomicAdd(&ssum[col], s1[threadIdx.x] + s1[threadIdx.x + 128]);
    atomicAdd(&ssq [col], s2[threadIdx.x] + s2[threadIdx.x + 128]);
  }
}

// BN params s,t and tw1[j] = sum_k t[k] * W1[k,j]   (single block, 128 threads)
__global__ void k_bn_tw1(const float* __restrict__ ssum, const float* __restrict__ ssq,
                         const float* __restrict__ gamma, const float* __restrict__ beta,
                         const float* __restrict__ W1,
                         float* __restrict__ sarr, float* __restrict__ tarr,
                         float* __restrict__ tw1) {
  __shared__ float ts[128];
  int j = threadIdx.x;
  float mean = ssum[j] * (1.f/NN);
  float var  = ssq[j] * (1.f/NN) - mean*mean;
  float s = gamma[j] * rsqrtf(var + BN_EPS);
  float t = beta[j] - mean*s;
  sarr[j] = s; tarr[j] = t; ts[j] = t;
  __syncthreads();
  float acc = 0.f;
  #pragma unroll 8
  for (int k = 0; k < 128; ++k) acc += ts[k] * W1[k*DD + j];
  tw1[j] = acc;
}

// ---------------- exclusive scan (3 pass) ----------------

__global__ void k_scan1(const int* __restrict__ cnt, int* __restrict__ rp, int* __restrict__ bsums) {
  __shared__ int sm[256];
  int tid = threadIdx.x;
  int base = blockIdx.x*1024 + tid*4;
  int4 v = make_int4(0,0,0,0);
  if (base + 3 < NN) v = *(const int4*)(cnt + base);
  else {
    if (base   < NN) v.x = cnt[base];
    if (base+1 < NN) v.y = cnt[base+1];
    if (base+2 < NN) v.z = cnt[base+2];
    if (base+3 < NN) v.w = cnt[base+3];
  }
  int p1 = v.x, p2 = p1 + v.y, p3 = p2 + v.z, tsum = p3 + v.w;
  sm[tid] = tsum; __syncthreads();
  for (int off = 1; off < 256; off <<= 1) {
    int t = (tid >= off) ? sm[tid - off] : 0; __syncthreads();
    sm[tid] += t; __syncthreads();
  }
  int inc = sm[tid];
  int excl = inc - tsum;
  if (base   < NN) rp[base]   = excl;
  if (base+1 < NN) rp[base+1] = excl + p1;
  if (base+2 < NN) rp[base+2] = excl + p2;
  if (base+3 < NN) rp[base+3] = excl + p3;
  if (tid == 255) bsums[blockIdx.x] = inc;
}

__global__ void k_scan2(int* __restrict__ bsums, int nb) {
  __shared__ int sm[256];
  int tid = threadIdx.x;
  int v = (tid < nb) ? bsums[tid] : 0;
  sm[tid] = v; __syncthreads();
  for (int off = 1; off < 256; off <<= 1) {
    int t = (tid >= off) ? sm[tid - off] : 0; __syncthreads();
    sm[tid] += t; __syncthreads();
  }
  if (tid < nb) bsums[tid] = sm[tid] - v;   // exclusive
}

// fused: finalize row pointers + cur + dinv
__global__ void k_scan3(int* __restrict__ rp, const int* __restrict__ bsums,
                        int* __restrict__ cur, const int* __restrict__ cnt,
                        float* __restrict__ dinv) {
  int i = blockIdx.x*256 + threadIdx.x;
  if (i < NN) {
    int val = rp[i] + bsums[i >> 10];
    rp[i] = val; cur[i] = val;
    dinv[i] = rsqrtf((float)(cnt[i] + 1));
  }
  if (i == 0) rp[NN] = NE;
}

__global__ void k_fill(const int* __restrict__ ei, const float* __restrict__ dinv,
                       int* __restrict__ cur, int2* __restrict__ pairs) {
  int e = blockIdx.x*256 + threadIdx.x;
  if (e < NE) {
    int s = ei[e], d = ei[NE + e];
    int pos = atomicAdd(&cur[d], 1);
    float cf = dinv[s] * dinv[d];
    pairs[pos] = make_int2(s, __float_as_int(cf));
  }
}

// ---------------- GEMM: C[N,128] = A'[N,128] @ W[128,128] (+ row add) ----------------
// One 128-row tile per block. 8x8 register blocking, K in quarters of 32.
// At[k][r] transposed A tile, Wl[k][j] row-major W tile -> all b128 fragment reads.
// Classic load->barrier->stage->barrier->compute per quarter; no persistent loop,
// no forced occupancy (LDS 33.8 KB caps at 4 blocks/CU; VGPRs free to ~130).

template<bool FUSE, bool ADDROW>
__global__ __launch_bounds__(256)
void k_gemm(const float* __restrict__ A, const float* __restrict__ W,
            float* __restrict__ C, const float* __restrict__ sarr,
            const float* __restrict__ tw1, const float* __restrict__ a1p)
{
  __shared__ float Wl[32][132];
  __shared__ float At[32][132];
  const int tid = threadIdx.x;
  const int tc = tid & 15, tr = tid >> 4;         // compute map: 16x16 thread grid
  const int j0 = tc * 8,  r0 = tr * 8;            // 8x8 per thread
  const int wc4 = (tid & 31) * 4, wr = tid >> 5;  // W staging map
  const int ac4 = (tid & 7) * 4,  ar = tid >> 3;  // A staging map
  const int t = blockIdx.x;

  float a1v = 0.f;
  if constexpr (FUSE) a1v = *a1p;

  float acc[8][8];
  #pragma unroll
  for (int i = 0; i < 8; ++i)
    #pragma unroll
    for (int j = 0; j < 8; ++j) acc[i][j] = 0.f;

  #pragma unroll
  for (int q = 0; q < 4; ++q) {
    float4 va[4], vw[4];
    #pragma unroll
    for (int i = 0; i < 4; ++i) {
      int r = t*128 + ar + 32*i; r = (r < NN) ? r : (NN-1);
      va[i] = *(const float4*)(A + (size_t)r*DD + q*32 + ac4);
    }
    const float* wp = W + (size_t)(q*32 + wr)*DD + wc4;
    #pragma unroll
    for (int i = 0; i < 4; ++i) vw[i] = *(const float4*)(wp + (size_t)i*8*DD);
    float4 s = make_float4(1.f,1.f,1.f,1.f);
    if constexpr (FUSE) s = *(const float4*)(sarr + q*32 + ac4);

    __syncthreads();   // previous quarter's compute done before LDS overwrite
    #pragma unroll
    for (int i = 0; i < 4; ++i) {
      float4 v = va[i];
      if constexpr (FUSE) {
        v.x = (v.x >= 0.f ? v.x : a1v*v.x) * s.x;
        v.y = (v.y >= 0.f ? v.y : a1v*v.y) * s.y;
        v.z = (v.z >= 0.f ? v.z : a1v*v.z) * s.z;
        v.w = (v.w >= 0.f ? v.w : a1v*v.w) * s.w;
      }
      int rr = ar + 32*i;
      At[ac4+0][rr] = v.x; At[ac4+1][rr] = v.y;
      At[ac4+2][rr] = v.z; At[ac4+3][rr] = v.w;
      *(float4*)&Wl[wr + 8*i][wc4] = vw[i];
    }
    __syncthreads();

    #pragma unroll 4
    for (int k = 0; k < 32; ++k) {
      float4 b0 = *(const float4*)&Wl[k][j0];
      float4 b1 = *(const float4*)&Wl[k][j0+4];
      float4 a0 = *(const float4*)&At[k][r0];
      float4 a1r = *(const float4*)&At[k][r0+4];
      float aa[8] = {a0.x,a0.y,a0.z,a0.w,a1r.x,a1r.y,a1r.z,a1r.w};
      float bb[8] = {b0.x,b0.y,b0.z,b0.w,b1.x,b1.y,b1.z,b1.w};
      #pragma unroll
      for (int i = 0; i < 8; ++i)
        #pragma unroll
        for (int j = 0; j < 8; ++j)
          acc[i][j] += aa[i]*bb[j];
    }
  }

  float tw[8] = {0,0,0,0,0,0,0,0};
  if constexpr (ADDROW) {
    float4 t0 = *(const float4*)(tw1 + j0);
    float4 t1 = *(const float4*)(tw1 + j0 + 4);
    tw[0]=t0.x; tw[1]=t0.y; tw[2]=t0.z; tw[3]=t0.w;
    tw[4]=t1.x; tw[5]=t1.y; tw[6]=t1.z; tw[7]=t1.w;
  }
  #pragma unroll
  for (int i = 0; i < 8; ++i) {
    int row = t*128 + r0 + i;
    if (row < NN) {
      float4 o0 = make_float4(acc[i][0]+tw[0], acc[i][1]+tw[1], acc[i][2]+tw[2], acc[i][3]+tw[3]);
      float4 o1 = make_float4(acc[i][4]+tw[4], acc[i][5]+tw[5], acc[i][6]+tw[6], acc[i][7]+tw[7]);
      float* cp = C + (size_t)row*DD + j0;
      *(float4*)cp = o0; *(float4*)(cp+4) = o1;
    }
  }
}

// ---------------- aggregation: one wave per node, edge-unrolled gathers ----------------

template<bool PRELU>
__global__ __launch_bounds__(256)
void k_agg(const float* __restrict__ h, const int* __restrict__ rp,
           const int2* __restrict__ pairs, const float* __restrict__ dinv,
           const float* __restrict__ bias, const float* __restrict__ a2p,
           float* __restrict__ out)
{
  int wave = threadIdx.x >> 6;
  int lane = threadIdx.x & 63;
  int node = blockIdx.x*4 + wave;
  if (node >= NN) return;
  const float2* h2 = (const float2*)h;
  float2* o2 = (float2*)out;
  int beg = rp[node], end = rp[node+1];
  float di = dinv[node];
  float2 self = h2[(size_t)node*64 + lane];
  float2 b = ((const float2*)bias)[lane];
  float a2 = 1.f;
  if constexpr (PRELU) a2 = *a2p;
  float sc = di*di;
  float ax = sc*self.x + b.x, ay = sc*self.y + b.y;
  int e = beg;
  for (; e + 4 <= end; e += 4) {
    int2 p0 = pairs[e], p1 = pairs[e+1], p2 = pairs[e+2], p3 = pairs[e+3];
    float2 g0 = h2[(size_t)p0.x*64 + lane];
    float2 g1 = h2[(size_t)p1.x*64 + lane];
    float2 g2 = h2[(size_t)p2.x*64 + lane];
    float2 g3 = h2[(size_t)p3.x*64 + lane];
    float c0 = __int_as_float(p0.y), c1 = __int_as_float(p1.y);
    float c2 = __int_as_float(p2.y), c3 = __int_as_float(p3.y);
    ax += c0*g0.x + c1*g1.x + c2*g2.x + c3*g3.x;
    ay += c0*g0.y + c1*g1.y + c2*g2.y + c3*g3.y;
  }
  if (e + 2 <= end) {
    int2 p0 = pairs[e], p1 = pairs[e+1];
    float2 g0 = h2[(size_t)p0.x*64 + lane];
    float2 g1 = h2[(size_t)p1.x*64 + lane];
    float c0 = __int_as_float(p0.y), c1 = __int_as_float(p1.y);
    ax += c0*g0.x + c1*g1.x;
    ay += c0*g0.y + c1*g1.y;
    e += 2;
  }
  if (e < end) {
    int2 p0 = pairs[e];
    float2 g0 = h2[(size_t)p0.x*64 + lane];
    float c0 = __int_as_float(p0.y);
    ax += c0*g0.x; ay += c0*g0.y;
  }
  if constexpr (PRELU) {
    ax = (ax >= 0.f) ? ax : a2*ax;
    ay = (ay >= 0.f) ? ay : a2*ay;
  }
  o2[(size_t)node*64 + lane] = make_float2(ax, ay);
}

// ---------------- launch ----------------

extern "C" void kernel_launch(void* const* d_in, const int* in_sizes, int n_in,
                              void* d_out, int out_size, void* d_ws, size_t ws_size,
                              hipStream_t stream) {
  const float* x     = (const float*)d_in[0];
  const int*   ei    = (const int*)  d_in[1];
  const float* a1    = (const float*)d_in[2];
  const float* gamma = (const float*)d_in[3];
  const float* beta  = (const float*)d_in[4];
  const float* W1    = (const float*)d_in[5];
  const float* b1    = (const float*)d_in[6];
  const float* a2    = (const float*)d_in[7];
  const float* W2    = (const float*)d_in[8];
  const float* b2    = (const float*)d_in[9];
  float* out = (float*)d_out;

  char* w = (char*)d_ws;
  auto alloc = [&](size_t bytes) { char* p = w; w += (bytes + 255) & ~(size_t)255; return p; };
  float* hbuf  = (float*)alloc((size_t)NN*DD*4);   // 102.4 MB
  float* dinv  = (float*)alloc((size_t)NN*4);
  int*   cnt   = (int*)  alloc((size_t)NN*4);
  int*   rp    = (int*)  alloc((size_t)(NN+1)*4);
  int*   cur   = (int*)  alloc((size_t)NN*4);
  int2*  pairs = (int2*) alloc((size_t)NE*8);
  int*   bsums = (int*)  alloc(256*4);
  float* ssum  = (float*)alloc(128*4);
  float* ssq   = (float*)alloc(128*4);
  float* sarr  = (float*)alloc(128*4);
  float* tarr  = (float*)alloc(128*4);
  float* tw1   = (float*)alloc(128*4);

  const int nblkN = (NN + 255)/256;
  const int nblkE = (NE + 255)/256;

  k_zero  <<<nblkN, 256, 0, stream>>>(cnt, ssum, ssq);
  k_count <<<nblkE, 256, 0, stream>>>(ei, cnt);
  k_stats <<<768,   256, 0, stream>>>(x, a1, ssum, ssq);
  k_bn_tw1<<<1,     128, 0, stream>>>(ssum, ssq, gamma, beta, W1, sarr, tarr, tw1);
  k_scan1 <<<196,   256, 0, stream>>>(cnt, rp, bsums);
  k_scan2 <<<1,     256, 0, stream>>>(bsums, 196);
  k_scan3 <<<nblkN, 256, 0, stream>>>(rp, bsums, cur, cnt, dinv);
  k_fill  <<<nblkE, 256, 0, stream>>>(ei, dinv, cur, pairs);

  k_gemm<true,  true ><<<GT, 256, 0, stream>>>(x,   W1, hbuf, sarr, tw1, a1);
  k_agg <true >        <<<NN/4, 256, 0, stream>>>(hbuf, rp, pairs, dinv, b1, a2, out);
  k_gemm<false, false><<<GT, 256, 0, stream>>>(out, W2, hbuf, nullptr, nullptr, nullptr);
  k_agg <false>        <<<NN/4, 256, 0, stream>>>(hbuf, rp, pairs, dinv, b2, nullptr, out);
}